// Round 5
// baseline (1274.247 us; speedup 1.0000x reference)
//
#include <hip/hip_runtime.h>
#include <hip/hip_cooperative_groups.h>
namespace cg = cooperative_groups;

#define BATCH 2
#define C 20
#define W 512
#define NPIX (512*512)
#define NW 16
#define NH 16
#define K 256
#define NITERS 10
#define SPLIT 4
#define PITCH 260          // LDS row pitch (floats), breaks pow2 stride
#define NEG_INF_F (-1.0e10f)
#define REC 189            // per-cell record: 9 j * (20 ch + 1 den)
#define PART_STRIDE 189

// ================================================================ PERSISTENT
// One block per (batch, cell). 4 px/thread in registers for the whole kernel
// (x read exactly once). 11 grid syncs; spf normalization done redundantly
// per block from ping-ponged per-cell records. LDS kept < 31.5 KB so 2
// blocks/CU co-residency is certain (512 blocks co-resident).
__global__ __launch_bounds__(256, 2)
void ssn_persist(const float* __restrict__ x,
                 float* __restrict__ bufA,
                 float* __restrict__ bufB,
                 float* __restrict__ outX,
                 float* __restrict__ outQ,
                 float* __restrict__ outSpf) {
    cg::grid_group grid = cg::this_grid();

    __shared__ float spf_lds[9][C];
    __shared__ float den_lds[9];
    __shared__ float sumsq_lds[9];
    __shared__ float chpart[80];
    __shared__ float pf_tile[C][PITCH];       // 20 rows only (no ones row)
    __shared__ float w_tile[9][PITCH];

    const int t    = threadIdx.x;
    const int bi   = blockIdx.x;            // 0..511
    const int cell = bi & (K - 1);
    const int b    = bi >> 8;
    const int ky = cell >> 4, kx = cell & 15;
    const int py = t >> 5, px = t & 31;
    const int xcol = kx * 32 + px;

    bool valid9[9];
#pragma unroll
    for (int j = 0; j < 9; ++j) {
        int ny = ky + j / 3 - 1, nx = kx + j % 3 - 1;
        valid9[j] = (ny >= 0 && ny < NH && nx >= 0 && nx < NW);
    }

    const int tile = t >> 4, lane = t & 15;
    const int jt = tile / 3, rt = tile % 3;   // output tile: j in 3jt.., r in 7rt..

    // ---------------- load x once (4 px/thread), fused outX copy
    float pf4[4][C];
    {
        const float* xb = x    + (size_t)b * C * NPIX;
        float*       ox = outX + (size_t)b * C * NPIX;
#pragma unroll
        for (int p = 0; p < 4; ++p) {
            int y = ky * 32 + p * 8 + py;
            const float* src = xb + (size_t)y * W + xcol;
            float*       dst = ox + (size_t)y * W + xcol;
#pragma unroll
            for (int ch = 0; ch < C; ++ch) {
                float v = src[(size_t)ch * NPIX];
                pf4[p][ch] = v;
                dst[(size_t)ch * NPIX] = v;
            }
        }
    }

    // ---------------- init record: cell sums as j=4 row, den=1024
#pragma unroll
    for (int ch = 0; ch < C; ++ch)
        pf_tile[ch][t] = pf4[0][ch] + pf4[1][ch] + pf4[2][ch] + pf4[3][ch];
    __syncthreads();
    if (t < 80) {
        int ch = t >> 2, q = t & 3;
        const float4* p = (const float4*)&pf_tile[ch][0];
        float s4 = 0.f;
#pragma unroll
        for (int i = 0; i < 16; ++i) {
            float4 v = p[q * 16 + i];
            s4 += v.x + v.y + v.z + v.w;
        }
        chpart[t] = s4;
    }
    __syncthreads();
    if (t < REC) {
        float v = 0.f;
        if (t >= 84 && t < 104) {
            int ch = t - 84;
            v = chpart[ch * 4] + chpart[ch * 4 + 1]
              + chpart[ch * 4 + 2] + chpart[ch * 4 + 3];
        } else if (t == 104) {
            v = 1024.0f;
        }
        bufA[(size_t)bi * REC + t] = v;
    }
    __threadfence();
    grid.sync();

    // ---------------- iterations
    for (int it = 0; it < NITERS; ++it) {
        const float* rp = (it & 1) ? bufB : bufA;
        float*       wp = (it & 1) ? bufA : bufB;
        const int last = (it == NITERS - 1);

        // phase 0: normalize 9 neighbor spf from records
        float numreg = 0.f;
        if (t < 180) {
            int jj = t / 20, ch = t % 20;
            if (valid9[jj]) {
                int ny = ky + jj / 3 - 1, nx = kx + jj % 3 - 1;
#pragma unroll
                for (int j2 = 0; j2 < 9; ++j2) {
                    int cy = ny - (j2 / 3 - 1), cx = nx - (j2 % 3 - 1);
                    if (cy >= 0 && cy < NH && cx >= 0 && cx < NW)
                        numreg += rp[(size_t)((b << 8) + cy * NW + cx) * REC
                                     + j2 * 21 + ch];
                }
            }
        }
        if (t >= 192 && t < 201) {
            int jj = t - 192;
            float den = 0.f;
            if (valid9[jj]) {
                int ny = ky + jj / 3 - 1, nx = kx + jj % 3 - 1;
#pragma unroll
                for (int j2 = 0; j2 < 9; ++j2) {
                    int cy = ny - (j2 / 3 - 1), cx = nx - (j2 % 3 - 1);
                    if (cy >= 0 && cy < NH && cx >= 0 && cx < NW)
                        den += rp[(size_t)((b << 8) + cy * NW + cx) * REC
                                  + j2 * 21 + 20];
                }
            }
            den_lds[jj] = den;
        }
        __syncthreads();
        if (t < 180) {
            int jj = t / 20, ch = t % 20;
            spf_lds[jj][ch] = numreg / fmaxf(den_lds[jj], 1e-8f);
        }
        __syncthreads();
        if (t < 9) {
            float ss2 = 0.f;
#pragma unroll
            for (int ch = 0; ch < C; ++ch) ss2 += spf_lds[t][ch] * spf_lds[t][ch];
            sumsq_lds[t] = ss2;
        }
        __syncthreads();

        // 4 passes of phase A (scores/softmax) + phase B (dot products)
        float acc[3][7];
#pragma unroll
        for (int jj = 0; jj < 3; ++jj)
#pragma unroll
            for (int rr = 0; rr < 7; ++rr) acc[jj][rr] = 0.f;

#pragma unroll
        for (int p = 0; p < 4; ++p) {
            float sc[9];
#pragma unroll
            for (int j = 0; j < 9; ++j) {
                float dot = 0.f;
#pragma unroll
                for (int ch = 0; ch < C; ++ch)
                    dot = fmaf(pf4[p][ch], spf_lds[j][ch], dot);
                sc[j] = valid9[j] ? fmaf(2.f, dot, -sumsq_lds[j]) : NEG_INF_F;
            }
            float m = sc[0];
#pragma unroll
            for (int j = 1; j < 9; ++j) m = fmaxf(m, sc[j]);
            float wv[9], wsum = 0.f;
#pragma unroll
            for (int j = 0; j < 9; ++j) { wv[j] = __expf(sc[j] - m); wsum += wv[j]; }
            float inv = 1.0f / wsum;
#pragma unroll
            for (int j = 0; j < 9; ++j) { wv[j] *= inv; w_tile[j][t] = wv[j]; }
#pragma unroll
            for (int ch = 0; ch < C; ++ch) pf_tile[ch][t] = pf4[p][ch];

            if (last) {
                int y = ky * 32 + p * 8 + py;
                float* q = outQ + (size_t)b * 9 * NPIX + (size_t)y * W + xcol;
#pragma unroll
                for (int j = 0; j < 9; ++j) q[(size_t)j * NPIX] = wv[j];
            }
            __syncthreads();

            if (t < 144) {
#pragma unroll
                for (int cc = 0; cc < 4; ++cc) {
                    int c4 = lane + (cc << 4);
                    float4 w4[3], f4[7];
#pragma unroll
                    for (int jj = 0; jj < 3; ++jj)
                        w4[jj] = ((const float4*)&w_tile[3 * jt + jj][0])[c4];
#pragma unroll
                    for (int rr = 0; rr < 7; ++rr) {
                        int r = 7 * rt + rr;
                        if (r < 20)
                            f4[rr] = ((const float4*)&pf_tile[r][0])[c4];
                    }
#pragma unroll
                    for (int jj = 0; jj < 3; ++jj)
#pragma unroll
                        for (int rr = 0; rr < 7; ++rr) {
                            int r = 7 * rt + rr;
                            if (r < 20) {
                                acc[jj][rr] = fmaf(w4[jj].x, f4[rr].x, acc[jj][rr]);
                                acc[jj][rr] = fmaf(w4[jj].y, f4[rr].y, acc[jj][rr]);
                                acc[jj][rr] = fmaf(w4[jj].z, f4[rr].z, acc[jj][rr]);
                                acc[jj][rr] = fmaf(w4[jj].w, f4[rr].w, acc[jj][rr]);
                            } else {   // r == 20: den column (implicit ones)
                                acc[jj][rr] += w4[jj].x + w4[jj].y
                                             + w4[jj].z + w4[jj].w;
                            }
                        }
                }
            }
            __syncthreads();
        }

        // write this cell's record (16-lane shfl tree per tile)
        if (t < 144) {
#pragma unroll
            for (int off = 8; off >= 1; off >>= 1)
#pragma unroll
                for (int jj = 0; jj < 3; ++jj)
#pragma unroll
                    for (int rr = 0; rr < 7; ++rr)
                        acc[jj][rr] += __shfl_down(acc[jj][rr], off);
            if (lane == 0) {
                float* dst = wp + (size_t)bi * REC;
#pragma unroll
                for (int jj = 0; jj < 3; ++jj)
#pragma unroll
                    for (int rr = 0; rr < 7; ++rr)
                        dst[(3 * jt + jj) * 21 + 7 * rt + rr] = acc[jj][rr];
            }
        }
        __threadfence();
        grid.sync();
    }

    // ---------------- final spf output (b,c,k); it==9 wrote bufA
    if (t < 20) {
        float num = 0.f, den = 0.f;
#pragma unroll
        for (int j2 = 0; j2 < 9; ++j2) {
            int cy = ky - (j2 / 3 - 1), cx = kx - (j2 % 3 - 1);
            if (cy >= 0 && cy < NH && cx >= 0 && cx < NW) {
                const float* rec = bufA + (size_t)((b << 8) + cy * NW + cx) * REC
                                 + j2 * 21;
                num += rec[t];
                den += rec[20];
            }
        }
        outSpf[((size_t)b * C + t) * K + cell] = num / fmaxf(den, 1e-8f);
    }
}

// ================================================================ FALLBACK
// (validated R3 path, used only if cooperative launch is rejected)
__global__ __launch_bounds__(256)
void ssn_init_kernel(const float* __restrict__ x,
                     float* __restrict__ outX,
                     float* __restrict__ wpart) {
    __shared__ float pf_tile[C][PITCH];
    __shared__ float chpart[80];
    int t = threadIdx.x;
    int bi = blockIdx.x;
    int s    = bi & 3;
    int cell = (bi >> 2) & (K - 1);
    int b    = bi >> 10;
    int ky = cell >> 4, kx = cell & 15;
    int py = t >> 5, px = t & 31;
    int y  = ky * 32 + s * 8 + py;
    int xx = kx * 32 + px;

    const float* xb = x    + (size_t)b * C * NPIX + y * W + xx;
    float*       ox = outX + (size_t)b * C * NPIX + y * W + xx;
#pragma unroll
    for (int ch = 0; ch < C; ++ch) {
        float v = xb[(size_t)ch * NPIX];
        ox[(size_t)ch * NPIX] = v;
        pf_tile[ch][t] = v;
    }
    __syncthreads();
    if (t < 80) {
        int ch = t >> 2, q = t & 3;
        const float4* p = (const float4*)&pf_tile[ch][0];
        float s4 = 0.f;
#pragma unroll
        for (int i = 0; i < 16; ++i) {
            float4 v = p[q * 16 + i];
            s4 += v.x + v.y + v.z + v.w;
        }
        chpart[t] = s4;
    }
    __syncthreads();
    if (t < PART_STRIDE) {
        float v = 0.f;
        if (t >= 84 && t < 104) {
            int ch = t - 84;
            v = chpart[ch * 4] + chpart[ch * 4 + 1]
              + chpart[ch * 4 + 2] + chpart[ch * 4 + 3];
        } else if (t == 104) {
            v = 256.0f;
        }
        wpart[(size_t)(b * K + cell) * (SPLIT * PART_STRIDE)
              + s * PART_STRIDE + t] = v;
    }
}

__global__ void ssn_reduce_kernel(const float* __restrict__ part,
                                  float* __restrict__ spf,
                                  float* __restrict__ outSpf,
                                  int final_mode) {
    int idx = blockIdx.x * blockDim.x + threadIdx.x;
    if (idx >= BATCH * K * C) return;
    int ch = idx % C;
    int k  = (idx / C) % K;
    int b  = idx / (C * K);
    int ky = k >> 4, kx = k & 15;
    float num = 0.f, den = 0.f;
#pragma unroll
    for (int j2 = 0; j2 < 9; ++j2) {
        int cy = ky - (j2 / 3 - 1), cx = kx - (j2 % 3 - 1);
        if (cy >= 0 && cy < NH && cx >= 0 && cx < NW) {
            const float* p = part +
                (size_t)(b * K + cy * NW + cx) * (SPLIT * PART_STRIDE) + j2 * 21;
#pragma unroll
            for (int ss = 0; ss < SPLIT; ++ss) {
                num += p[ss * PART_STRIDE + ch];
                den += p[ss * PART_STRIDE + 20];
            }
        }
    }
    float v = num / fmaxf(den, 1e-8f);
    if (final_mode) outSpf[(b * C + ch) * K + k] = v;
    else            spf[(b * K + k) * C + ch]    = v;
}

__global__ __launch_bounds__(256)
void ssn_iterate_kernel(const float* __restrict__ x,
                        const float* __restrict__ spf,
                        float* __restrict__ wpart,
                        float* __restrict__ outQ,
                        int last) {
    __shared__ float spf_lds[9][C];
    __shared__ float sumsq_lds[9];
    __shared__ float pf_tile[C + 1][PITCH];
    __shared__ float w_tile[9][PITCH];

    int t = threadIdx.x;
    int bi = blockIdx.x;
    int s    = bi & 3;
    int cell = (bi >> 2) & (K - 1);
    int b    = bi >> 10;
    int ky = cell >> 4, kx = cell & 15;

    int py = t >> 5, px = t & 31;
    int y  = ky * 32 + s * 8 + py;
    int xx = kx * 32 + px;

    float pf[C];
    const float* xb = x + (size_t)b * C * NPIX + y * W + xx;
#pragma unroll
    for (int ch = 0; ch < C; ++ch) pf[ch] = xb[(size_t)ch * NPIX];

    if (t < 9 * C) {
        int jj = t / C, ch = t % C;
        int ny = ky + jj / 3 - 1, nx = kx + jj % 3 - 1;
        float v = 0.f;
        if (ny >= 0 && ny < NH && nx >= 0 && nx < NW)
            v = spf[(size_t)(b * K + ny * NW + nx) * C + ch];
        spf_lds[jj][ch] = v;
    }
    if (t < 9) {
        int ny = ky + t / 3 - 1, nx = kx + t % 3 - 1;
        float ss2 = 0.f;
        if (ny >= 0 && ny < NH && nx >= 0 && nx < NW) {
            const float* sp = spf + (size_t)(b * K + ny * NW + nx) * C;
#pragma unroll
            for (int ch = 0; ch < C; ++ch) ss2 += sp[ch] * sp[ch];
        }
        sumsq_lds[t] = ss2;
    }
    __syncthreads();

    float sc[9];
#pragma unroll
    for (int j = 0; j < 9; ++j) {
        int ny = ky + j / 3 - 1, nx = kx + j % 3 - 1;
        bool valid = (ny >= 0 && ny < NH && nx >= 0 && nx < NW);
        float dot = 0.f;
#pragma unroll
        for (int ch = 0; ch < C; ++ch) dot = fmaf(pf[ch], spf_lds[j][ch], dot);
        sc[j] = valid ? fmaf(2.f, dot, -sumsq_lds[j]) : NEG_INF_F;
    }
    float m = sc[0];
#pragma unroll
    for (int j = 1; j < 9; ++j) m = fmaxf(m, sc[j]);
    float wv[9], wsum = 0.f;
#pragma unroll
    for (int j = 0; j < 9; ++j) { wv[j] = __expf(sc[j] - m); wsum += wv[j]; }
    float inv = 1.0f / wsum;
#pragma unroll
    for (int j = 0; j < 9; ++j) { wv[j] *= inv; w_tile[j][t] = wv[j]; }
#pragma unroll
    for (int ch = 0; ch < C; ++ch) pf_tile[ch][t] = pf[ch];
    pf_tile[C][t] = 1.0f;

    if (last) {
        float* q = outQ + (size_t)b * 9 * NPIX + y * W + xx;
#pragma unroll
        for (int j = 0; j < 9; ++j) q[(size_t)j * NPIX] = wv[j];
    }
    __syncthreads();

    if (t < 144) {
        int tile = t >> 4;
        int lane = t & 15;
        int jt = tile / 3;
        int rt = tile % 3;
        float acc[3][7];
#pragma unroll
        for (int jj = 0; jj < 3; ++jj)
#pragma unroll
            for (int rr = 0; rr < 7; ++rr) acc[jj][rr] = 0.f;

#pragma unroll
        for (int cc = 0; cc < 4; ++cc) {
            int c4 = lane + (cc << 4);
            float4 w4[3], f4[7];
#pragma unroll
            for (int jj = 0; jj < 3; ++jj)
                w4[jj] = ((const float4*)&w_tile[3 * jt + jj][0])[c4];
#pragma unroll
            for (int rr = 0; rr < 7; ++rr)
                f4[rr] = ((const float4*)&pf_tile[7 * rt + rr][0])[c4];
#pragma unroll
            for (int jj = 0; jj < 3; ++jj)
#pragma unroll
                for (int rr = 0; rr < 7; ++rr) {
                    acc[jj][rr] = fmaf(w4[jj].x, f4[rr].x, acc[jj][rr]);
                    acc[jj][rr] = fmaf(w4[jj].y, f4[rr].y, acc[jj][rr]);
                    acc[jj][rr] = fmaf(w4[jj].z, f4[rr].z, acc[jj][rr]);
                    acc[jj][rr] = fmaf(w4[jj].w, f4[rr].w, acc[jj][rr]);
                }
        }
#pragma unroll
        for (int off = 8; off >= 1; off >>= 1)
#pragma unroll
            for (int jj = 0; jj < 3; ++jj)
#pragma unroll
                for (int rr = 0; rr < 7; ++rr)
                    acc[jj][rr] += __shfl_down(acc[jj][rr], off);
        if (lane == 0) {
            float* dst = wpart + (size_t)(b * K + cell) * (SPLIT * PART_STRIDE)
                       + s * PART_STRIDE;
#pragma unroll
            for (int jj = 0; jj < 3; ++jj)
#pragma unroll
                for (int rr = 0; rr < 7; ++rr)
                    dst[(3 * jt + jj) * 21 + 7 * rt + rr] = acc[jj][rr];
        }
    }
}

// ================================================================ launch
extern "C" void kernel_launch(void* const* d_in, const int* in_sizes, int n_in,
                              void* d_out, int out_size, void* d_ws, size_t ws_size,
                              hipStream_t stream) {
    const float* x = (const float*)d_in[0];
    float* out = (float*)d_out;
    float* outQ   = out;                                   // B*9*NPIX
    float* outSpf = out + (size_t)BATCH * 9 * NPIX;        // B*C*K
    float* outX   = outSpf + (size_t)BATCH * C * K;        // B*C*NPIX

    float* ws   = (float*)d_ws;
    float* bufA = ws;                                      // B*K*REC (coop)
    float* bufB = bufA + (size_t)BATCH * K * REC;
    float* spf  = bufB + (size_t)BATCH * K * REC;          // fallback scratch
    float* part = spf + (size_t)BATCH * K * C;

    void* args[] = {(void*)&x, (void*)&bufA, (void*)&bufB,
                    (void*)&outX, (void*)&outQ, (void*)&outSpf};
    hipError_t err = hipLaunchCooperativeKernel((const void*)ssn_persist,
                                                dim3(BATCH * K), dim3(256),
                                                args, 0, stream);
    if (err != hipSuccess) {
        // fallback: validated multi-kernel path
        ssn_init_kernel<<<BATCH * K * SPLIT, 256, 0, stream>>>(x, outX, part);
        ssn_reduce_kernel<<<160, 64, 0, stream>>>(part, spf, nullptr, 0);
        for (int it = 0; it < NITERS; ++it) {
            ssn_iterate_kernel<<<BATCH * K * SPLIT, 256, 0, stream>>>(
                x, spf, part, outQ, (it == NITERS - 1) ? 1 : 0);
            if (it < NITERS - 1)
                ssn_reduce_kernel<<<160, 64, 0, stream>>>(part, spf, nullptr, 0);
        }
        ssn_reduce_kernel<<<160, 64, 0, stream>>>(part, nullptr, outSpf, 1);
    }
}

// Round 6
// 402.831 us; speedup vs baseline: 3.1632x; 3.1632x over previous
//
#include <hip/hip_runtime.h>

#define BATCH 2
#define C 20
#define W 512
#define NPIX (512*512)
#define NW 16
#define NH 16
#define K 256
#define NITERS 10
#define PITCH 260          // LDS row pitch (floats); rows 16B-aligned
#define NEG_INF_F (-1.0e10f)
#define REC 189            // per-cell record: 9 j * (20 ch + 1 den)

// ---------------------------------------------------------------- init
// One block per (b, cell): 4 px/thread. Copies x -> outX, stores cell-mean
// record directly into bufA (j=4 row = channel sums, den = 1024), and zeroes
// this cell's record in bufB (the it=0 accumulation target).
__global__ __launch_bounds__(256)
void ssn_init_kernel(const float* __restrict__ x,
                     float* __restrict__ outX,
                     float* __restrict__ bufA,
                     float* __restrict__ bufB) {
    __shared__ float pf_tile[C][PITCH];
    __shared__ float chpart[80];
    const int t    = threadIdx.x;
    const int bi   = blockIdx.x;           // 0..511 = b*256 + cell
    const int cell = bi & (K - 1);
    const int b    = bi >> 8;
    const int ky = cell >> 4, kx = cell & 15;
    const int py = t >> 5, px = t & 31;
    const int xcol = kx * 32 + px;

    const float* xb = x    + (size_t)b * C * NPIX;
    float*       ox = outX + (size_t)b * C * NPIX;
    float sum4[C];
#pragma unroll
    for (int ch = 0; ch < C; ++ch) sum4[ch] = 0.f;
#pragma unroll
    for (int p = 0; p < 4; ++p) {
        int y = ky * 32 + p * 8 + py;
        const float* src = xb + (size_t)y * W + xcol;
        float*       dst = ox + (size_t)y * W + xcol;
#pragma unroll
        for (int ch = 0; ch < C; ++ch) {
            float v = src[(size_t)ch * NPIX];
            sum4[ch] += v;
            dst[(size_t)ch * NPIX] = v;
        }
    }
#pragma unroll
    for (int ch = 0; ch < C; ++ch) pf_tile[ch][t] = sum4[ch];
    __syncthreads();
    if (t < 80) {
        int ch = t >> 2, q = t & 3;
        const float4* p = (const float4*)&pf_tile[ch][0];
        float s4 = 0.f;
#pragma unroll
        for (int i = 0; i < 16; ++i) {
            float4 v = p[q * 16 + i];
            s4 += v.x + v.y + v.z + v.w;
        }
        chpart[t] = s4;
    }
    __syncthreads();
    if (t < REC) {
        float v = 0.f;
        if (t >= 84 && t < 104) {
            int ch = t - 84;
            v = chpart[ch * 4] + chpart[ch * 4 + 1]
              + chpart[ch * 4 + 2] + chpart[ch * 4 + 3];
        } else if (t == 104) {
            v = 1024.0f;
        }
        bufA[(size_t)bi * REC + t] = v;
        bufB[(size_t)bi * REC + t] = 0.f;   // it=0 accumulation target
    }
}

// ---------------------------------------------------------------- iterate
// Block = (b, cell, split): 256 px. Phase 0: normalize 9 neighbor spf from
// per-cell records in rp. Phase A: scores 2<pf,spf>-|spf|^2, softmax.
// Phase B: 9x21 register-tiled dot products -> atomicAdd into wp's per-cell
// record. Split-0 blocks also zero zp (next-next iteration's target).
__global__ __launch_bounds__(256)
void ssn_iterate_kernel(const float* __restrict__ x,
                        const float* __restrict__ rp,
                        float* __restrict__ wp,
                        float* __restrict__ zp,
                        float* __restrict__ outQ,
                        int last) {
    __shared__ float spf_lds[9][C];
    __shared__ float den_lds[9];
    __shared__ float sumsq_lds[9];
    __shared__ float pf_tile[C][PITCH];   // no ones-row; den via w-sum
    __shared__ float w_tile[9][PITCH];

    const int t  = threadIdx.x;
    const int bi = blockIdx.x;
    const int s    = bi & 3;
    const int cell = (bi >> 2) & (K - 1);
    const int b    = bi >> 10;
    const int bcell = (b << 8) + cell;
    const int ky = cell >> 4, kx = cell & 15;
    const int py = t >> 5, px = t & 31;
    const int y  = ky * 32 + s * 8 + py;
    const int xcol = kx * 32 + px;

    // zero the buffer that iteration it+1 will accumulate into
    if (s == 0 && t < REC) zp[(size_t)bcell * REC + t] = 0.f;

    // hoisted x loads (L3-resident after init) — in flight across phase 0
    float pf[C];
    const float* xb = x + (size_t)b * C * NPIX + (size_t)y * W + xcol;
#pragma unroll
    for (int ch = 0; ch < C; ++ch) pf[ch] = xb[(size_t)ch * NPIX];

    // ---- phase 0: normalize neighbor spf from per-cell records
    float numreg = 0.f;
    if (t < 180) {
        int jj = t / 20, ch = t % 20;
        int ny = ky + jj / 3 - 1, nx = kx + jj % 3 - 1;
        if (ny >= 0 && ny < NH && nx >= 0 && nx < NW) {
#pragma unroll
            for (int j2 = 0; j2 < 9; ++j2) {
                int cy = ny - (j2 / 3 - 1), cx = nx - (j2 % 3 - 1);
                if (cy >= 0 && cy < NH && cx >= 0 && cx < NW)
                    numreg += rp[(size_t)((b << 8) + cy * NW + cx) * REC
                                 + j2 * 21 + ch];
            }
        }
    }
    if (t >= 192 && t < 201) {
        int jj = t - 192;
        int ny = ky + jj / 3 - 1, nx = kx + jj % 3 - 1;
        float den = 0.f;
        if (ny >= 0 && ny < NH && nx >= 0 && nx < NW) {
#pragma unroll
            for (int j2 = 0; j2 < 9; ++j2) {
                int cy = ny - (j2 / 3 - 1), cx = nx - (j2 % 3 - 1);
                if (cy >= 0 && cy < NH && cx >= 0 && cx < NW)
                    den += rp[(size_t)((b << 8) + cy * NW + cx) * REC
                              + j2 * 21 + 20];
            }
        }
        den_lds[jj] = den;
    }
    __syncthreads();
    if (t < 180) {
        int jj = t / 20, ch = t % 20;
        spf_lds[jj][ch] = numreg / fmaxf(den_lds[jj], 1e-8f);
    }
    __syncthreads();
    if (t < 9) {
        float ss2 = 0.f;
#pragma unroll
        for (int ch = 0; ch < C; ++ch) ss2 += spf_lds[t][ch] * spf_lds[t][ch];
        sumsq_lds[t] = ss2;
    }
    __syncthreads();

    // ---- phase A: scores + softmax
    float sc[9];
#pragma unroll
    for (int j = 0; j < 9; ++j) {
        int ny = ky + j / 3 - 1, nx = kx + j % 3 - 1;
        bool valid = (ny >= 0 && ny < NH && nx >= 0 && nx < NW);
        float dot = 0.f;
#pragma unroll
        for (int ch = 0; ch < C; ++ch) dot = fmaf(pf[ch], spf_lds[j][ch], dot);
        sc[j] = valid ? fmaf(2.f, dot, -sumsq_lds[j]) : NEG_INF_F;
    }
    float m = sc[0];
#pragma unroll
    for (int j = 1; j < 9; ++j) m = fmaxf(m, sc[j]);
    float wv[9], wsum = 0.f;
#pragma unroll
    for (int j = 0; j < 9; ++j) { wv[j] = __expf(sc[j] - m); wsum += wv[j]; }
    float inv = 1.0f / wsum;
#pragma unroll
    for (int j = 0; j < 9; ++j) { wv[j] *= inv; w_tile[j][t] = wv[j]; }
#pragma unroll
    for (int ch = 0; ch < C; ++ch) pf_tile[ch][t] = pf[ch];

    if (last) {
        float* q = outQ + (size_t)b * 9 * NPIX + (size_t)y * W + xcol;
#pragma unroll
        for (int j = 0; j < 9; ++j) q[(size_t)j * NPIX] = wv[j];
    }
    __syncthreads();

    // ---- phase B: 9x21 outputs, 3x3 tiles of (3j x 7r), 16 lanes/tile
    if (t < 144) {
        const int tile = t >> 4, lane = t & 15;
        const int jt = tile / 3, rt = tile % 3;
        float acc[3][7];
#pragma unroll
        for (int jj = 0; jj < 3; ++jj)
#pragma unroll
            for (int rr = 0; rr < 7; ++rr) acc[jj][rr] = 0.f;

#pragma unroll
        for (int cc = 0; cc < 4; ++cc) {
            int c4 = lane + (cc << 4);
            float4 w4[3], f4[7];
#pragma unroll
            for (int jj = 0; jj < 3; ++jj)
                w4[jj] = ((const float4*)&w_tile[3 * jt + jj][0])[c4];
#pragma unroll
            for (int rr = 0; rr < 7; ++rr) {
                int r = 7 * rt + rr;
                if (r < 20) f4[rr] = ((const float4*)&pf_tile[r][0])[c4];
            }
#pragma unroll
            for (int jj = 0; jj < 3; ++jj)
#pragma unroll
                for (int rr = 0; rr < 7; ++rr) {
                    int r = 7 * rt + rr;
                    if (r < 20) {
                        acc[jj][rr] = fmaf(w4[jj].x, f4[rr].x, acc[jj][rr]);
                        acc[jj][rr] = fmaf(w4[jj].y, f4[rr].y, acc[jj][rr]);
                        acc[jj][rr] = fmaf(w4[jj].z, f4[rr].z, acc[jj][rr]);
                        acc[jj][rr] = fmaf(w4[jj].w, f4[rr].w, acc[jj][rr]);
                    } else {          // r == 20: den column (implicit ones)
                        acc[jj][rr] += w4[jj].x + w4[jj].y
                                     + w4[jj].z + w4[jj].w;
                    }
                }
        }
#pragma unroll
        for (int off = 8; off >= 1; off >>= 1)
#pragma unroll
            for (int jj = 0; jj < 3; ++jj)
#pragma unroll
                for (int rr = 0; rr < 7; ++rr)
                    acc[jj][rr] += __shfl_down(acc[jj][rr], off);
        if (lane == 0) {
            float* dst = wp + (size_t)bcell * REC;
#pragma unroll
            for (int jj = 0; jj < 3; ++jj)
#pragma unroll
                for (int rr = 0; rr < 7; ++rr)
                    atomicAdd(&dst[(3 * jt + jj) * 21 + 7 * rt + rr],
                              acc[jj][rr]);
        }
    }
}

// ---------------------------------------------------------------- final spf
__global__ void ssn_final_kernel(const float* __restrict__ rec,
                                 float* __restrict__ outSpf) {
    int idx = blockIdx.x * blockDim.x + threadIdx.x;   // B*K*C
    if (idx >= BATCH * K * C) return;
    int ch = idx % C;
    int k  = (idx / C) % K;
    int b  = idx / (C * K);
    int ky = k >> 4, kx = k & 15;
    float num = 0.f, den = 0.f;
#pragma unroll
    for (int j2 = 0; j2 < 9; ++j2) {
        int cy = ky - (j2 / 3 - 1), cx = kx - (j2 % 3 - 1);
        if (cy >= 0 && cy < NH && cx >= 0 && cx < NW) {
            const float* p = rec + (size_t)((b << 8) + cy * NW + cx) * REC
                           + j2 * 21;
            num += p[ch];
            den += p[20];
        }
    }
    outSpf[((size_t)b * C + ch) * K + k] = num / fmaxf(den, 1e-8f);
}

// ---------------------------------------------------------------- launch
extern "C" void kernel_launch(void* const* d_in, const int* in_sizes, int n_in,
                              void* d_out, int out_size, void* d_ws, size_t ws_size,
                              hipStream_t stream) {
    const float* x = (const float*)d_in[0];
    float* out = (float*)d_out;
    float* outQ   = out;                                   // B*9*NPIX
    float* outSpf = out + (size_t)BATCH * 9 * NPIX;        // B*C*K
    float* outX   = outSpf + (size_t)BATCH * C * K;        // B*C*NPIX

    float* ws = (float*)d_ws;
    float* buf[3];
    buf[0] = ws;                                           // B*K*REC each
    buf[1] = buf[0] + (size_t)BATCH * K * REC;
    buf[2] = buf[1] + (size_t)BATCH * K * REC;

    // init: x copy + cell-mean record into buf0; zero buf1
    ssn_init_kernel<<<BATCH * K, 256, 0, stream>>>(x, outX, buf[0], buf[1]);

    for (int it = 0; it < NITERS; ++it) {
        const float* rp = buf[it % 3];
        float*       wp = buf[(it + 1) % 3];
        float*       zp = buf[(it + 2) % 3];
        ssn_iterate_kernel<<<BATCH * K * 4, 256, 0, stream>>>(
            x, rp, wp, zp, outQ, (it == NITERS - 1) ? 1 : 0);
    }
    // it==9 wrote buf[10%3] = buf[1]
    ssn_final_kernel<<<(BATCH * K * C + 255) / 256, 256, 0, stream>>>(
        buf[1], outSpf);
}

// Round 7
// 299.869 us; speedup vs baseline: 4.2493x; 1.3434x over previous
//
#include <hip/hip_runtime.h>

#define BATCH 2
#define C 20
#define W 512
#define NPIX (512*512)
#define NW 16
#define NH 16
#define K 256
#define NITERS 10
#define SPLIT 4
#define PITCH 260          // LDS row pitch (floats)
#define NEG_INF_F (-1.0e10f)
#define REC 189            // payload: 9 j * (20 ch + 1 den)
#define RECP 192           // padded record stride (768 B = 12 lines)

// ---------------------------------------------------------------- init
// One block per (b, cell): 4 px/thread. Copies x -> outX, writes the cell
// record in split format: slot 0 = {j=4 row: channel sums, den=1024},
// slots 1..3 = zeros.
__global__ __launch_bounds__(256)
void ssn_init_kernel(const float* __restrict__ x,
                     float* __restrict__ outX,
                     float* __restrict__ buf0) {
    __shared__ float pf_tile[C][PITCH];
    __shared__ float chpart[80];
    const int t    = threadIdx.x;
    const int bi   = blockIdx.x;           // 0..511 = b*256 + cell
    const int cell = bi & (K - 1);
    const int b    = bi >> 8;
    const int ky = cell >> 4, kx = cell & 15;
    const int py = t >> 5, px = t & 31;
    const int xcol = kx * 32 + px;

    const float* xb = x    + (size_t)b * C * NPIX;
    float*       ox = outX + (size_t)b * C * NPIX;
    float sum4[C];
#pragma unroll
    for (int ch = 0; ch < C; ++ch) sum4[ch] = 0.f;
#pragma unroll
    for (int p = 0; p < 4; ++p) {
        int y = ky * 32 + p * 8 + py;
        const float* src = xb + (size_t)y * W + xcol;
        float*       dst = ox + (size_t)y * W + xcol;
#pragma unroll
        for (int ch = 0; ch < C; ++ch) {
            float v = src[(size_t)ch * NPIX];
            sum4[ch] += v;
            dst[(size_t)ch * NPIX] = v;
        }
    }
#pragma unroll
    for (int ch = 0; ch < C; ++ch) pf_tile[ch][t] = sum4[ch];
    __syncthreads();
    if (t < 80) {
        int ch = t >> 2, q = t & 3;
        const float4* p = (const float4*)&pf_tile[ch][0];
        float s4 = 0.f;
#pragma unroll
        for (int i = 0; i < 16; ++i) {
            float4 v = p[q * 16 + i];
            s4 += v.x + v.y + v.z + v.w;
        }
        chpart[t] = s4;
    }
    __syncthreads();
    if (t < REC) {
        float v = 0.f;
        if (t >= 84 && t < 104) {
            int ch = t - 84;
            v = chpart[ch * 4] + chpart[ch * 4 + 1]
              + chpart[ch * 4 + 2] + chpart[ch * 4 + 3];
        } else if (t == 104) {
            v = 1024.0f;
        }
        float* base = buf0 + (size_t)bi * (SPLIT * RECP);
        base[t] = v;                       // split 0
        base[RECP + t] = 0.f;              // splits 1..3 zero
        base[2 * RECP + t] = 0.f;
        base[3 * RECP + t] = 0.f;
    }
}

// ---------------------------------------------------------------- iterate
// Block = (b, cell, split): 256 px. Phase 0: normalize 9 neighbor spf by
// gathering 9 j2 x 4 split rows per neighbor from rp (36 independent loads
// per thread, plain-store records). Phase A: scores 2<pf,spf>-|spf|^2,
// softmax. Phase B: 9x21 register-tiled dot products -> own split slot
// (plain stores, no atomics).
__global__ __launch_bounds__(256)
void ssn_iterate_kernel(const float* __restrict__ x,
                        const float* __restrict__ rp,
                        float* __restrict__ wp,
                        float* __restrict__ outQ,
                        int last) {
    __shared__ float spf_lds[9][C];
    __shared__ float den_lds[9];
    __shared__ float sumsq_lds[9];
    __shared__ float pf_tile[C][PITCH];
    __shared__ float w_tile[9][PITCH];

    const int t  = threadIdx.x;
    const int bi = blockIdx.x;
    const int s    = bi & 3;
    const int cell = (bi >> 2) & (K - 1);
    const int b    = bi >> 10;
    const int bcell = (b << 8) + cell;
    const int ky = cell >> 4, kx = cell & 15;
    const int py = t >> 5, px = t & 31;
    const int y  = ky * 32 + s * 8 + py;
    const int xcol = kx * 32 + px;

    // hoisted x loads (L2/L3-resident after init) — in flight across phase 0
    float pf[C];
    const float* xb = x + (size_t)b * C * NPIX + (size_t)y * W + xcol;
#pragma unroll
    for (int ch = 0; ch < C; ++ch) pf[ch] = xb[(size_t)ch * NPIX];

    // ---- phase 0: gather + normalize neighbor spf from split-records
    float numreg = 0.f;
    if (t < 180) {
        int jj = t / 20, ch = t % 20;
        int ny = ky + jj / 3 - 1, nx = kx + jj % 3 - 1;
        if (ny >= 0 && ny < NH && nx >= 0 && nx < NW) {
#pragma unroll
            for (int j2 = 0; j2 < 9; ++j2) {
                int cy = ny - (j2 / 3 - 1), cx = nx - (j2 % 3 - 1);
                if (cy >= 0 && cy < NH && cx >= 0 && cx < NW) {
                    const float* p = rp +
                        (size_t)((b << 8) + cy * NW + cx) * (SPLIT * RECP)
                        + j2 * 21 + ch;
#pragma unroll
                    for (int ss = 0; ss < SPLIT; ++ss)
                        numreg += p[ss * RECP];
                }
            }
        }
    }
    if (t >= 192 && t < 201) {
        int jj = t - 192;
        int ny = ky + jj / 3 - 1, nx = kx + jj % 3 - 1;
        float den = 0.f;
        if (ny >= 0 && ny < NH && nx >= 0 && nx < NW) {
#pragma unroll
            for (int j2 = 0; j2 < 9; ++j2) {
                int cy = ny - (j2 / 3 - 1), cx = nx - (j2 % 3 - 1);
                if (cy >= 0 && cy < NH && cx >= 0 && cx < NW) {
                    const float* p = rp +
                        (size_t)((b << 8) + cy * NW + cx) * (SPLIT * RECP)
                        + j2 * 21 + 20;
#pragma unroll
                    for (int ss = 0; ss < SPLIT; ++ss)
                        den += p[ss * RECP];
                }
            }
        }
        den_lds[jj] = den;
    }
    __syncthreads();
    if (t < 180) {
        int jj = t / 20, ch = t % 20;
        spf_lds[jj][ch] = numreg / fmaxf(den_lds[jj], 1e-8f);
    }
    __syncthreads();
    if (t < 9) {
        float ss2 = 0.f;
#pragma unroll
        for (int ch = 0; ch < C; ++ch) ss2 += spf_lds[t][ch] * spf_lds[t][ch];
        sumsq_lds[t] = ss2;
    }
    __syncthreads();

    // ---- phase A: scores + softmax
    float sc[9];
#pragma unroll
    for (int j = 0; j < 9; ++j) {
        int ny = ky + j / 3 - 1, nx = kx + j % 3 - 1;
        bool valid = (ny >= 0 && ny < NH && nx >= 0 && nx < NW);
        float dot = 0.f;
#pragma unroll
        for (int ch = 0; ch < C; ++ch) dot = fmaf(pf[ch], spf_lds[j][ch], dot);
        sc[j] = valid ? fmaf(2.f, dot, -sumsq_lds[j]) : NEG_INF_F;
    }
    float m = sc[0];
#pragma unroll
    for (int j = 1; j < 9; ++j) m = fmaxf(m, sc[j]);
    float wv[9], wsum = 0.f;
#pragma unroll
    for (int j = 0; j < 9; ++j) { wv[j] = __expf(sc[j] - m); wsum += wv[j]; }
    float inv = 1.0f / wsum;
#pragma unroll
    for (int j = 0; j < 9; ++j) { wv[j] *= inv; w_tile[j][t] = wv[j]; }
#pragma unroll
    for (int ch = 0; ch < C; ++ch) pf_tile[ch][t] = pf[ch];

    if (last) {
        float* q = outQ + (size_t)b * 9 * NPIX + (size_t)y * W + xcol;
#pragma unroll
        for (int j = 0; j < 9; ++j) q[(size_t)j * NPIX] = wv[j];
    }
    __syncthreads();

    // ---- phase B: 9x21 outputs, 3x3 tiles of (3j x 7r), 16 lanes/tile
    if (t < 144) {
        const int tile = t >> 4, lane = t & 15;
        const int jt = tile / 3, rt = tile % 3;
        float acc[3][7];
#pragma unroll
        for (int jj = 0; jj < 3; ++jj)
#pragma unroll
            for (int rr = 0; rr < 7; ++rr) acc[jj][rr] = 0.f;

#pragma unroll
        for (int cc = 0; cc < 4; ++cc) {
            int c4 = lane + (cc << 4);
            float4 w4[3], f4[7];
#pragma unroll
            for (int jj = 0; jj < 3; ++jj)
                w4[jj] = ((const float4*)&w_tile[3 * jt + jj][0])[c4];
#pragma unroll
            for (int rr = 0; rr < 7; ++rr) {
                int r = 7 * rt + rr;
                if (r < 20) f4[rr] = ((const float4*)&pf_tile[r][0])[c4];
            }
#pragma unroll
            for (int jj = 0; jj < 3; ++jj)
#pragma unroll
                for (int rr = 0; rr < 7; ++rr) {
                    int r = 7 * rt + rr;
                    if (r < 20) {
                        acc[jj][rr] = fmaf(w4[jj].x, f4[rr].x, acc[jj][rr]);
                        acc[jj][rr] = fmaf(w4[jj].y, f4[rr].y, acc[jj][rr]);
                        acc[jj][rr] = fmaf(w4[jj].z, f4[rr].z, acc[jj][rr]);
                        acc[jj][rr] = fmaf(w4[jj].w, f4[rr].w, acc[jj][rr]);
                    } else {          // r == 20: den column (implicit ones)
                        acc[jj][rr] += w4[jj].x + w4[jj].y
                                     + w4[jj].z + w4[jj].w;
                    }
                }
        }
#pragma unroll
        for (int off = 8; off >= 1; off >>= 1)
#pragma unroll
            for (int jj = 0; jj < 3; ++jj)
#pragma unroll
                for (int rr = 0; rr < 7; ++rr)
                    acc[jj][rr] += __shfl_down(acc[jj][rr], off);
        if (lane == 0) {
            float* dst = wp + (size_t)bcell * (SPLIT * RECP) + s * RECP;
#pragma unroll
            for (int jj = 0; jj < 3; ++jj)
#pragma unroll
                for (int rr = 0; rr < 7; ++rr)
                    dst[(3 * jt + jj) * 21 + 7 * rt + rr] = acc[jj][rr];
        }
    }
}

// ---------------------------------------------------------------- final spf
__global__ void ssn_final_kernel(const float* __restrict__ part,
                                 float* __restrict__ outSpf) {
    int idx = blockIdx.x * blockDim.x + threadIdx.x;   // B*K*C
    if (idx >= BATCH * K * C) return;
    int ch = idx % C;
    int k  = (idx / C) % K;
    int b  = idx / (C * K);
    int ky = k >> 4, kx = k & 15;
    float num = 0.f, den = 0.f;
#pragma unroll
    for (int j2 = 0; j2 < 9; ++j2) {
        int cy = ky - (j2 / 3 - 1), cx = kx - (j2 % 3 - 1);
        if (cy >= 0 && cy < NH && cx >= 0 && cx < NW) {
            const float* p = part +
                (size_t)((b << 8) + cy * NW + cx) * (SPLIT * RECP) + j2 * 21;
#pragma unroll
            for (int ss = 0; ss < SPLIT; ++ss) {
                num += p[ss * RECP + ch];
                den += p[ss * RECP + 20];
            }
        }
    }
    outSpf[((size_t)b * C + ch) * K + k] = num / fmaxf(den, 1e-8f);
}

// ---------------------------------------------------------------- launch
extern "C" void kernel_launch(void* const* d_in, const int* in_sizes, int n_in,
                              void* d_out, int out_size, void* d_ws, size_t ws_size,
                              hipStream_t stream) {
    const float* x = (const float*)d_in[0];
    float* out = (float*)d_out;
    float* outQ   = out;                                   // B*9*NPIX
    float* outSpf = out + (size_t)BATCH * 9 * NPIX;        // B*C*K
    float* outX   = outSpf + (size_t)BATCH * C * K;        // B*C*NPIX

    float* ws = (float*)d_ws;
    float* buf0 = ws;                                      // B*K*SPLIT*RECP
    float* buf1 = buf0 + (size_t)BATCH * K * SPLIT * RECP;

    // init: x copy + cell-mean split-record into buf0
    ssn_init_kernel<<<BATCH * K, 256, 0, stream>>>(x, outX, buf0);

    for (int it = 0; it < NITERS; ++it) {
        const float* rp = (it & 1) ? buf1 : buf0;
        float*       wp = (it & 1) ? buf0 : buf1;
        ssn_iterate_kernel<<<BATCH * K * SPLIT, 256, 0, stream>>>(
            x, rp, wp, outQ, (it == NITERS - 1) ? 1 : 0);
    }
    // it==9 wrote buf0
    ssn_final_kernel<<<(BATCH * K * C + 255) / 256, 256, 0, stream>>>(
        buf0, outSpf);
}

// Round 8
// 264.531 us; speedup vs baseline: 4.8170x; 1.1336x over previous
//
#include <hip/hip_runtime.h>

#define BATCH 2
#define C 20
#define W 512
#define NPIX (512*512)
#define NW 16
#define NH 16
#define K 256
#define NITERS 10
#define PITCH 260          // LDS row pitch (floats)
#define NEG_INF_F (-1.0e10f)
#define REC 189            // payload: 9 j * (20 ch + 1 den)
#define RECP 192           // padded record stride

// ---------------------------------------------------------------- init
// One block per (b, cell): 4 px/thread. Copies x -> outX, writes the cell
// record: j=4 row = channel sums, den = 1024, rest 0.
__global__ __launch_bounds__(256)
void ssn_init_kernel(const float* __restrict__ x,
                     float* __restrict__ outX,
                     float* __restrict__ buf0) {
    __shared__ float pf_tile[C][PITCH];
    __shared__ float chpart[80];
    const int t    = threadIdx.x;
    const int bi   = blockIdx.x;           // 0..511 = b*256 + cell
    const int cell = bi & (K - 1);
    const int b    = bi >> 8;
    const int ky = cell >> 4, kx = cell & 15;
    const int py = t >> 5, px = t & 31;
    const int xcol = kx * 32 + px;

    const float* xb = x    + (size_t)b * C * NPIX;
    float*       ox = outX + (size_t)b * C * NPIX;
    float sum4[C];
#pragma unroll
    for (int ch = 0; ch < C; ++ch) sum4[ch] = 0.f;
#pragma unroll
    for (int p = 0; p < 4; ++p) {
        int y = ky * 32 + p * 8 + py;
        const float* src = xb + (size_t)y * W + xcol;
        float*       dst = ox + (size_t)y * W + xcol;
#pragma unroll
        for (int ch = 0; ch < C; ++ch) {
            float v = src[(size_t)ch * NPIX];
            sum4[ch] += v;
            dst[(size_t)ch * NPIX] = v;
        }
    }
#pragma unroll
    for (int ch = 0; ch < C; ++ch) pf_tile[ch][t] = sum4[ch];
    __syncthreads();
    if (t < 80) {
        int ch = t >> 2, q = t & 3;
        const float4* p = (const float4*)&pf_tile[ch][0];
        float s4 = 0.f;
#pragma unroll
        for (int i = 0; i < 16; ++i) {
            float4 v = p[q * 16 + i];
            s4 += v.x + v.y + v.z + v.w;
        }
        chpart[t] = s4;
    }
    __syncthreads();
    if (t < REC) {
        float v = 0.f;
        if (t >= 84 && t < 104) {
            int ch = t - 84;
            v = chpart[ch * 4] + chpart[ch * 4 + 1]
              + chpart[ch * 4 + 2] + chpart[ch * 4 + 3];
        } else if (t == 104) {
            v = 1024.0f;
        }
        buf0[(size_t)bi * RECP + t] = v;
    }
}

// ---------------------------------------------------------------- iterate
// One block per (b, cell): 1024 px via 4 passes of 256. Phase 0: normalize
// 9 neighbor spf from single per-cell records (9 loads/thread). Phases A+B
// per pass: scores 2<pf,spf>-|spf|^2, softmax, 9x21 register-tiled dot
// products accumulated across passes; one record store at the end.
__global__ __launch_bounds__(256, 2)
void ssn_iterate_kernel(const float* __restrict__ x,
                        const float* __restrict__ rp,
                        float* __restrict__ wp,
                        float* __restrict__ outQ,
                        int last) {
    __shared__ float spf_lds[9][C];
    __shared__ float den_lds[9];
    __shared__ float sumsq_lds[9];
    __shared__ float pf_tile[C][PITCH];
    __shared__ float w_tile[9][PITCH];

    const int t    = threadIdx.x;
    const int bi   = blockIdx.x;           // 0..511
    const int cell = bi & (K - 1);
    const int b    = bi >> 8;
    const int ky = cell >> 4, kx = cell & 15;
    const int py = t >> 5, px = t & 31;
    const int xcol = kx * 32 + px;

    // ---- load x once (4 px/thread) — in flight across phase 0
    float pf4[4][C];
    {
        const float* xb = x + (size_t)b * C * NPIX;
#pragma unroll
        for (int p = 0; p < 4; ++p) {
            int y = ky * 32 + p * 8 + py;
            const float* src = xb + (size_t)y * W + xcol;
#pragma unroll
            for (int ch = 0; ch < C; ++ch)
                pf4[p][ch] = src[(size_t)ch * NPIX];
        }
    }

    // ---- phase 0: gather + normalize neighbor spf (9 loads/thread)
    float numreg = 0.f;
    if (t < 180) {
        int jj = t / 20, ch = t % 20;
        int ny = ky + jj / 3 - 1, nx = kx + jj % 3 - 1;
        if (ny >= 0 && ny < NH && nx >= 0 && nx < NW) {
#pragma unroll
            for (int j2 = 0; j2 < 9; ++j2) {
                int cy = ny - (j2 / 3 - 1), cx = nx - (j2 % 3 - 1);
                if (cy >= 0 && cy < NH && cx >= 0 && cx < NW)
                    numreg += rp[(size_t)((b << 8) + cy * NW + cx) * RECP
                                 + j2 * 21 + ch];
            }
        }
    }
    if (t >= 192 && t < 201) {
        int jj = t - 192;
        int ny = ky + jj / 3 - 1, nx = kx + jj % 3 - 1;
        float den = 0.f;
        if (ny >= 0 && ny < NH && nx >= 0 && nx < NW) {
#pragma unroll
            for (int j2 = 0; j2 < 9; ++j2) {
                int cy = ny - (j2 / 3 - 1), cx = nx - (j2 % 3 - 1);
                if (cy >= 0 && cy < NH && cx >= 0 && cx < NW)
                    den += rp[(size_t)((b << 8) + cy * NW + cx) * RECP
                              + j2 * 21 + 20];
            }
        }
        den_lds[jj] = den;
    }
    __syncthreads();
    if (t < 180) {
        int jj = t / 20, ch = t % 20;
        spf_lds[jj][ch] = numreg / fmaxf(den_lds[jj], 1e-8f);
    }
    __syncthreads();
    if (t < 9) {
        float ss2 = 0.f;
#pragma unroll
        for (int ch = 0; ch < C; ++ch) ss2 += spf_lds[t][ch] * spf_lds[t][ch];
        sumsq_lds[t] = ss2;
    }
    __syncthreads();

    // block-uniform validity
    bool valid9[9];
#pragma unroll
    for (int j = 0; j < 9; ++j) {
        int ny = ky + j / 3 - 1, nx = kx + j % 3 - 1;
        valid9[j] = (ny >= 0 && ny < NH && nx >= 0 && nx < NW);
    }

    const int tile = t >> 4, lane = t & 15;
    const int jt = tile / 3, rt = tile % 3;

    float acc[3][7];
#pragma unroll
    for (int jj = 0; jj < 3; ++jj)
#pragma unroll
        for (int rr = 0; rr < 7; ++rr) acc[jj][rr] = 0.f;

    // ---- 4 passes: phase A (scores/softmax) + phase B (dot products)
#pragma unroll
    for (int p = 0; p < 4; ++p) {
        float sc[9];
#pragma unroll
        for (int j = 0; j < 9; ++j) {
            float dot = 0.f;
#pragma unroll
            for (int ch = 0; ch < C; ++ch)
                dot = fmaf(pf4[p][ch], spf_lds[j][ch], dot);
            sc[j] = valid9[j] ? fmaf(2.f, dot, -sumsq_lds[j]) : NEG_INF_F;
        }
        float m = sc[0];
#pragma unroll
        for (int j = 1; j < 9; ++j) m = fmaxf(m, sc[j]);
        float wv[9], wsum = 0.f;
#pragma unroll
        for (int j = 0; j < 9; ++j) { wv[j] = __expf(sc[j] - m); wsum += wv[j]; }
        float inv = 1.0f / wsum;
#pragma unroll
        for (int j = 0; j < 9; ++j) { wv[j] *= inv; w_tile[j][t] = wv[j]; }
#pragma unroll
        for (int ch = 0; ch < C; ++ch) pf_tile[ch][t] = pf4[p][ch];

        if (last) {
            int y = ky * 32 + p * 8 + py;
            float* q = outQ + (size_t)b * 9 * NPIX + (size_t)y * W + xcol;
#pragma unroll
            for (int j = 0; j < 9; ++j) q[(size_t)j * NPIX] = wv[j];
        }
        __syncthreads();

        if (t < 144) {
#pragma unroll
            for (int cc = 0; cc < 4; ++cc) {
                int c4 = lane + (cc << 4);
                float4 w4[3], f4[7];
#pragma unroll
                for (int jj = 0; jj < 3; ++jj)
                    w4[jj] = ((const float4*)&w_tile[3 * jt + jj][0])[c4];
#pragma unroll
                for (int rr = 0; rr < 7; ++rr) {
                    int r = 7 * rt + rr;
                    if (r < 20) f4[rr] = ((const float4*)&pf_tile[r][0])[c4];
                }
#pragma unroll
                for (int jj = 0; jj < 3; ++jj)
#pragma unroll
                    for (int rr = 0; rr < 7; ++rr) {
                        int r = 7 * rt + rr;
                        if (r < 20) {
                            acc[jj][rr] = fmaf(w4[jj].x, f4[rr].x, acc[jj][rr]);
                            acc[jj][rr] = fmaf(w4[jj].y, f4[rr].y, acc[jj][rr]);
                            acc[jj][rr] = fmaf(w4[jj].z, f4[rr].z, acc[jj][rr]);
                            acc[jj][rr] = fmaf(w4[jj].w, f4[rr].w, acc[jj][rr]);
                        } else {      // r == 20: den column (implicit ones)
                            acc[jj][rr] += w4[jj].x + w4[jj].y
                                         + w4[jj].z + w4[jj].w;
                        }
                    }
            }
        }
        __syncthreads();
    }

    // ---- record store: 16-lane shfl tree per tile, plain stores
    if (t < 144) {
#pragma unroll
        for (int off = 8; off >= 1; off >>= 1)
#pragma unroll
            for (int jj = 0; jj < 3; ++jj)
#pragma unroll
                for (int rr = 0; rr < 7; ++rr)
                    acc[jj][rr] += __shfl_down(acc[jj][rr], off);
        if (lane == 0) {
            float* dst = wp + (size_t)bi * RECP;
#pragma unroll
            for (int jj = 0; jj < 3; ++jj)
#pragma unroll
                for (int rr = 0; rr < 7; ++rr)
                    dst[(3 * jt + jj) * 21 + 7 * rt + rr] = acc[jj][rr];
        }
    }
}

// ---------------------------------------------------------------- final spf
__global__ void ssn_final_kernel(const float* __restrict__ rec,
                                 float* __restrict__ outSpf) {
    int idx = blockIdx.x * blockDim.x + threadIdx.x;   // B*K*C
    if (idx >= BATCH * K * C) return;
    int ch = idx % C;
    int k  = (idx / C) % K;
    int b  = idx / (C * K);
    int ky = k >> 4, kx = k & 15;
    float num = 0.f, den = 0.f;
#pragma unroll
    for (int j2 = 0; j2 < 9; ++j2) {
        int cy = ky - (j2 / 3 - 1), cx = kx - (j2 % 3 - 1);
        if (cy >= 0 && cy < NH && cx >= 0 && cx < NW) {
            const float* p = rec + (size_t)((b << 8) + cy * NW + cx) * RECP
                           + j2 * 21;
            num += p[ch];
            den += p[20];
        }
    }
    outSpf[((size_t)b * C + ch) * K + k] = num / fmaxf(den, 1e-8f);
}

// ---------------------------------------------------------------- launch
extern "C" void kernel_launch(void* const* d_in, const int* in_sizes, int n_in,
                              void* d_out, int out_size, void* d_ws, size_t ws_size,
                              hipStream_t stream) {
    const float* x = (const float*)d_in[0];
    float* out = (float*)d_out;
    float* outQ   = out;                                   // B*9*NPIX
    float* outSpf = out + (size_t)BATCH * 9 * NPIX;        // B*C*K
    float* outX   = outSpf + (size_t)BATCH * C * K;        // B*C*NPIX

    float* ws = (float*)d_ws;
    float* buf0 = ws;                                      // B*K*RECP
    float* buf1 = buf0 + (size_t)BATCH * K * RECP;

    ssn_init_kernel<<<BATCH * K, 256, 0, stream>>>(x, outX, buf0);

    for (int it = 0; it < NITERS; ++it) {
        const float* rpb = (it & 1) ? buf1 : buf0;
        float*       wpb = (it & 1) ? buf0 : buf1;
        ssn_iterate_kernel<<<BATCH * K, 256, 0, stream>>>(
            x, rpb, wpb, outQ, (it == NITERS - 1) ? 1 : 0);
    }
    // it==9 read buf1, wrote buf0
    ssn_final_kernel<<<(BATCH * K * C + 255) / 256, 256, 0, stream>>>(
        buf0, outSpf);
}